// Round 12
// baseline (111.092 us; speedup 1.0000x reference)
//
#include <hip/hip_runtime.h>
#include <math.h>

// ---------------- problem constants ----------------
#define DD   256
#define NSB  4
#define PPB  4
#define POSB 16
#define LL   2048
#define BB   2
#define NC   64         // time chunks
#define CHK  32         // LL/NC
#define NG   13         // groups: 0=cross, 1-4 banks, 5-8 pos, 9-12 ltm (4 complex slots each)
#define FS   128        // feature row stride (floats)
#define PI_F 3.14159265358979323846f

// feature row offsets (floats)
#define JK_OFF   0
#define JQ_OFF   8
#define KP_OFF   16
#define QP_OFF   48
#define LKP_OFF  80
#define GATE_OFF 112

// workspace layout (float offsets) — ws_size is ~256 MiB, plenty
#define FEAT_O  0L
#define V_O     524288L                  // BB*LL*FS
#define LV_O    1572864L                 // V_O + BB*LL*DD
#define PPH_O   2621440L                 // LV_O + BB*LL*DD
#define TOT_O   2686976L                 // PPH_O + LL*32
#define CMEM_O  3735552L                 // TOT_O + BB*LL*DD ; size BB*NG*NC*8*DD = 3407872
#define WGB_O   7143424L                 // CMEM_O + 3407872
#define TOT2_O  7151616L                 // WGB_O + BB*LL*2
#define OWT_O   8200192L                 // TOT2_O + BB*LL*DD ; owt 128*64*8 ush = 32768 floats
#define WS_FLOATS 8232960L               // (~32.9 MB)
// aliases inside the CMEM region (all dead before m_chunksum writes cmem):
#define KM_O    CMEM_O                   // g_prefix output, BB*LL*40 = 163840 floats
#define XH_O    CMEM_O                   // prep buffers, consumed by mlp_fused
#define XL_O    (CMEM_O + 524288L)
#define WTH_O   (CMEM_O + 1048576L)      // 96*8*64*8 ushort = 196608 floats
#define WT2H_O  (CMEM_O + 1245184L)      // 3*16*256 ushort = 6144 floats; end 1251328 <= 3407872

typedef __attribute__((ext_vector_type(8))) short bf16x8;
typedef __attribute__((ext_vector_type(4))) float f32x4;

__device__ __forceinline__ float sigm(float v){ return 1.0f/(1.0f+expf(-v)); }
__device__ __forceinline__ float gelu_exact(float v){ return 0.5f*v*(1.0f+erff(v*0.70710678118654752f)); }
__device__ __forceinline__ unsigned short f2bf(float f){
    unsigned u = __float_as_uint(f);
    unsigned r = u + 0x7fffu + ((u>>16)&1u);
    return (unsigned short)(r>>16);
}
__device__ __forceinline__ float bf2f(unsigned short h){ return __uint_as_float(((unsigned)h)<<16); }

// ---------------- PREP (merged): fragment-packed x / W1 / W2 / oW / pos phasors ----------------
// grid = 512 (x) + 192 (W1) + 48 (W2) + 8 (posph) + 32 (oW) = 792
__global__ __launch_bounds__(256) void prep_all(
    const float* __restrict__ x,
    const float* __restrict__ kW1, const float* __restrict__ qW1, const float* __restrict__ lW1,
    const float* __restrict__ vW,  const float* __restrict__ lvW, const float* __restrict__ gW1,
    const float* __restrict__ kW2, const float* __restrict__ qW2, const float* __restrict__ lW2,
    const float* __restrict__ oW,  const float* __restrict__ pf,
    unsigned short* __restrict__ xh, unsigned short* __restrict__ xl,
    unsigned short* __restrict__ wth, unsigned short* __restrict__ wt2h,
    unsigned short* __restrict__ owt, float* __restrict__ posph)
{
    int bid = blockIdx.x, tid = threadIdx.x;
    if (bid < 512){
        int gid = bid*256 + tid;          // (4096/16)*8*64
        int frag = gid>>6, lane = gid&63;
        int tile = frag>>3, ksb = frag&7;
        int row = tile*16 + (lane&15);
        int k0  = ksb*32 + ((lane>>4)&3)*8;
        const float* xp = x + (long)row*DD + k0;
        unsigned short h8[8], l8[8];
        #pragma unroll
        for (int e=0;e<8;++e){
            float f = xp[e];
            unsigned short h = f2bf(f);
            h8[e] = h;
            l8[e] = f2bf(f - bf2f(h));
        }
        *(bf16x8*)(xh + (long)gid*8) = *(bf16x8*)h8;
        *(bf16x8*)(xl + (long)gid*8) = *(bf16x8*)l8;
    } else if (bid < 512+192){
        int gid = (bid-512)*256 + tid;    // 96*8*64
        int frag = gid>>6, lane = gid&63;
        int tile = frag>>3, ksb = frag&7;
        int col = tile*16 + (lane&15);
        int k0  = ksb*32 + ((lane>>4)&3)*8;
        unsigned short h8[8];
        #pragma unroll
        for (int e=0;e<8;++e){
            int fi = k0 + e;
            float w = 0.f;
            if (col < 1408){
                int m = col >> 8;
                if (m < 5){
                    const float* W = (m==0)?kW1:((m==1)?qW1:((m==2)?lW1:((m==3)?vW:lvW)));
                    w = W[(long)fi*DD + (col & 255)];
                } else {
                    w = gW1[(long)fi*128 + (col - 1280)];
                }
            }
            h8[e] = f2bf(w);
        }
        *(bf16x8*)(wth + (long)gid*8) = *(bf16x8*)h8;
    } else if (bid < 512+192+48){
        int blk = bid - (512+192);
        int m = blk>>4, o = blk&15;
        const float* W2 = (m==0)?kW2:((m==1)?qW2:lW2);
        wt2h[(long)blk*DD + tid] = f2bf(W2[tid*16+o]);
    } else if (bid < 512+192+48+8){
        int t = (bid - (512+192+48))*256 + tid;
        if (t < LL){
            #pragma unroll
            for (int j=0;j<POSB;++j){
                float ang = (((float)t * pf[j]) * 2.0f) * PI_F;
                float s,c; sincosf(ang,&s,&c);
                posph[t*32+2*j]   = c;
                posph[t*32+2*j+1] = s;
            }
        }
    } else {
        // ---- oW^T fragment-packed (hi only): 128 frags x 64 lanes ----
        int gid = (bid - (512+192+48+8))*256 + tid;   // 0..8191
        int frag = gid>>6, lane = gid&63;
        int tile = frag>>3, ksb = frag&7;
        int col = tile*16 + (lane&15);
        int k0  = ksb*32 + ((lane>>4)&3)*8;
        unsigned short h8[8];
        #pragma unroll
        for (int e=0;e<8;++e)
            h8[e] = f2bf(oW[(long)(k0+e)*DD + col]);
        *(bf16x8*)(owt + (long)gid*8) = *(bf16x8*)h8;
    }
}

// ---------------- MLP fused: MFMA GEMM, 2-deep prefetch pipeline ----------------
__global__ __launch_bounds__(256) void mlp_fused(
    const unsigned short* __restrict__ xh, const unsigned short* __restrict__ xl,
    const unsigned short* __restrict__ wth, const unsigned short* __restrict__ wt2h,
    const float* __restrict__ kb1, const float* __restrict__ kb2,
    const float* __restrict__ qb1, const float* __restrict__ qb2,
    const float* __restrict__ lb1, const float* __restrict__ lb2,
    const float* __restrict__ vb,  const float* __restrict__ lvb,
    const float* __restrict__ gb1, const float* __restrict__ gW2, const float* __restrict__ gb2,
    float* __restrict__ feat, float* __restrict__ Vbuf, float* __restrict__ lvalbuf)
{
    __shared__ __align__(16) char smraw[18432];
    int tid = threadIdx.x, lane = tid & 63, wv = tid >> 6;
    int mat = blockIdx.x >> 7, bm = blockIdx.x & 127;
    int rowg0 = bm*32;
    int ar = lane & 15, kk = (lane>>4)*8;

    f32x4 acc[2][4];
    #pragma unroll
    for (int i=0;i<2;++i)
        #pragma unroll
        for (int j=0;j<4;++j) acc[i][j] = (f32x4){0.f,0.f,0.f,0.f};

    // ---- GEMM1: 2-deep software pipeline over 3 rotating fragment sets ----
    bf16x8 ah[3][2], al[3][2], bh[3][4];
    #pragma unroll
    for (int s=0;s<2;++s){
        #pragma unroll
        for (int i=0;i<2;++i){
            long off = (((long)(2*bm+i)*8 + s)*64 + lane)*8;
            ah[s][i] = *reinterpret_cast<const bf16x8*>(xh + off);
            al[s][i] = *reinterpret_cast<const bf16x8*>(xl + off);
        }
        #pragma unroll
        for (int j=0;j<4;++j){
            long off = (((long)(mat*16 + wv*4 + j)*8 + s)*64 + lane)*8;
            bh[s][j] = *reinterpret_cast<const bf16x8*>(wth + off);
        }
    }
    #pragma unroll
    for (int ksb=0; ksb<8; ++ksb){
        int cur = ksb % 3;
        if (ksb+2 < 8){
            int nxt = (ksb+2) % 3;
            #pragma unroll
            for (int i=0;i<2;++i){
                long off = (((long)(2*bm+i)*8 + ksb+2)*64 + lane)*8;
                ah[nxt][i] = *reinterpret_cast<const bf16x8*>(xh + off);
                al[nxt][i] = *reinterpret_cast<const bf16x8*>(xl + off);
            }
            #pragma unroll
            for (int j=0;j<4;++j){
                long off = (((long)(mat*16 + wv*4 + j)*8 + ksb+2)*64 + lane)*8;
                bh[nxt][j] = *reinterpret_cast<const bf16x8*>(wth + off);
            }
        }
        #pragma unroll
        for (int i=0;i<2;++i)
            #pragma unroll
            for (int j=0;j<4;++j){
                acc[i][j] = __builtin_amdgcn_mfma_f32_16x16x32_bf16(ah[cur][i], bh[cur][j], acc[i][j], 0,0,0);
                acc[i][j] = __builtin_amdgcn_mfma_f32_16x16x32_bf16(al[cur][i], bh[cur][j], acc[i][j], 0,0,0);
            }
    }

    int rl0 = (lane>>4)*4;

    if (mat < 3){
        float (*ang)[16] = (float(*)[16])(smraw + 16384);
        const float* b1 = (mat==0)?kb1:((mat==1)?qb1:lb1);
        #pragma unroll
        for (int i=0;i<2;++i)
            #pragma unroll
            for (int j=0;j<4;++j){
                int c = wv*64 + j*16 + ar;
                #pragma unroll
                for (int r=0;r<4;++r){
                    int row = i*16 + rl0 + r;
                    float hv = gelu_exact(acc[i][j][r] + b1[c]);
                    int bo = row*512 + c*2;
                    *(unsigned short*)(smraw + (bo ^ ((row&7)<<4))) = f2bf(hv);
                }
            }
        __syncthreads();
        const float* b2 = (mat==0)?kb2:((mat==1)?qb2:lb2);
        int off = (mat==0)?KP_OFF:((mat==1)?QP_OFF:LKP_OFF);
        if (wv < 2){
            int arow = wv*16 + ar;
            f32x4 a2 = (f32x4){0.f,0.f,0.f,0.f};
            #pragma unroll
            for (int ksb=0; ksb<8; ++ksb){
                int k = ksb*32 + kk;
                int bo = arow*512 + k*2;
                bf16x8 af = *reinterpret_cast<const bf16x8*>(smraw + (bo ^ ((arow&7)<<4)));
                bf16x8 bf = *reinterpret_cast<const bf16x8*>(wt2h + ((long)(mat*16 + ar)*DD + k));
                a2 = __builtin_amdgcn_mfma_f32_16x16x32_bf16(af, bf, a2, 0,0,0);
            }
            int o = ar;
            #pragma unroll
            for (int r=0;r<4;++r){
                int tok = wv*16 + rl0 + r;
                float a = tanhf(a2[r] + b2[o])*PI_F;
                ang[tok][o] = a;
                float sn,cs; sincosf(a,&sn,&cs);
                long rowg = rowg0 + tok;
                feat[rowg*FS + off + 2*o]   = cs;
                feat[rowg*FS + off + 2*o+1] = sn;
            }
        }
        __syncthreads();
        if (mat<2 && tid<128){
            int tok = tid>>2, p = tid&3;
            float a = ang[tok][p]+ang[tok][4+p]+ang[tok][8+p]+ang[tok][12+p];
            float sn,cs; sincosf(a,&sn,&cs);
            int joff = (mat==0)?JK_OFF:JQ_OFF;
            long rowg = rowg0 + tok;
            feat[rowg*FS + joff + 2*p]   = cs;
            feat[rowg*FS + joff + 2*p+1] = sn;
        }
    } else if (mat < 5){
        const float* bv = (mat==3)? vb : lvb;
        float* dst = (mat==3)? Vbuf : lvalbuf;
        #pragma unroll
        for (int i=0;i<2;++i)
            #pragma unroll
            for (int j=0;j<4;++j){
                int c = wv*64 + j*16 + ar;
                #pragma unroll
                for (int r=0;r<4;++r)
                    dst[(long)(rowg0 + i*16 + rl0 + r)*DD + c] = acc[i][j][r] + bv[c];
            }
    } else {
        float (*hg)[132] = (float(*)[132])smraw;
        float (*part)[8] = (float(*)[8])(smraw + 32*132*4);
        if (wv < 2){
            #pragma unroll
            for (int i=0;i<2;++i)
                #pragma unroll
                for (int j=0;j<4;++j){
                    int c = wv*64 + j*16 + ar;
                    #pragma unroll
                    for (int r=0;r<4;++r)
                        hg[i*16 + rl0 + r][c] = gelu_exact(acc[i][j][r] + gb1[c]);
                }
        }
        __syncthreads();
        {
            int tok = tid>>3, jj = tid&7;
            float s = 0.f;
            #pragma unroll
            for (int c=0;c<16;++c) s += hg[tok][jj*16+c]*gW2[jj*16+c];
            part[tok][jj] = s;
        }
        __syncthreads();
        if (tid < 32){
            float s = gb2[0];
            #pragma unroll
            for (int j=0;j<8;++j) s += part[tid][j];
            feat[(long)(rowg0+tid)*FS + GATE_OFF] = sigm(s);
        }
    }
}

// ---------------- G-A: float4 exclusive prefix of 10 channel-quads ----------------
// grid = BB*10, 256 threads; thread owns 8 tokens, quad = 4 channels
__global__ __launch_bounds__(256) void g_prefix4(const float* __restrict__ feat, float* __restrict__ km){
    int b = blockIdx.x / 10, q = blockIdx.x % 10;
    int off = (q<2) ? (JK_OFF + q*4) : (LKP_OFF + (q-2)*4);
    int tid = threadIdx.x;
    long rb = (long)b*LL*FS;
    float4 v[8]; float4 s = {0.f,0.f,0.f,0.f};
    #pragma unroll
    for (int u=0;u<8;++u){
        v[u] = *(const float4*)&feat[rb + (long)(tid*8+u)*FS + off];
        s.x += v[u].x; s.y += v[u].y; s.z += v[u].z; s.w += v[u].w;
    }
    int lane = tid & 63, w = tid >> 6;
    float4 xs = s;
    #pragma unroll
    for (int o=1;o<64;o<<=1){
        float yx = __shfl_up(xs.x,o), yy = __shfl_up(xs.y,o);
        float yz = __shfl_up(xs.z,o), yw = __shfl_up(xs.w,o);
        if (lane>=o){ xs.x += yx; xs.y += yy; xs.z += yz; xs.w += yw; }
    }
    __shared__ float4 wsum[4];
    if (lane==63) wsum[w] = xs;
    __syncthreads();
    float4 woff = {0.f,0.f,0.f,0.f};
    for (int i=0;i<w;++i){
        woff.x += wsum[i].x; woff.y += wsum[i].y; woff.z += wsum[i].z; woff.w += wsum[i].w;
    }
    float4 run = {xs.x - s.x + woff.x, xs.y - s.y + woff.y,
                  xs.z - s.z + woff.z, xs.w - s.w + woff.w};
    #pragma unroll
    for (int u=0;u<8;++u){
        *(float4*)&km[((long)b*LL + tid*8+u)*40 + q*4] = run;
        run.x += v[u].x; run.y += v[u].y; run.z += v[u].z; run.w += v[u].w;
    }
}

// ---------------- G-B: per-token familiarity + write gates (float4) ----------------
__global__ __launch_bounds__(64) void g_fam(
    const float* __restrict__ feat, const float* __restrict__ km,
    const float* __restrict__ ss_p, const float* __restrict__ sb_p,
    float* __restrict__ wgbuf)
{
    int t = blockIdx.x*64 + threadIdx.x;
    if (t >= BB*LL) return;
    int tc = t % LL;
    float ss = ss_p[0], sb = sb_p[0];
    long frow = (long)t*FS;
    const float* kmrow = km + (long)t*40;
    float pcb = fmaxf((float)tc, 1.0f);

    float sr=0.f, si=0.f;
    #pragma unroll
    for (int h=0;h<2;++h){
        float4 jk = *(const float4*)&feat[frow+JK_OFF+h*4];
        float4 m  = *(const float4*)&kmrow[h*4];
        sr += m.x*jk.x + m.y*jk.y;  si += m.y*jk.x - m.x*jk.y;
        sr += m.z*jk.z + m.w*jk.w;  si += m.w*jk.z - m.z*jk.w;
    }
    float res = sqrtf(sr*sr+si*si);
    float fam = fminf(fmaxf(res/(pcb*2.0f),0.f),1.f);
    wgbuf[(long)t*2] = sigm(ss*(0.5f-fam)+sb);

    sr=0.f; si=0.f;
    #pragma unroll
    for (int h=0;h<8;++h){
        float4 lk = *(const float4*)&feat[frow+LKP_OFF+h*4];
        float4 m  = *(const float4*)&kmrow[8+h*4];
        sr += m.x*lk.x + m.y*lk.y;  si += m.y*lk.x - m.x*lk.y;
        sr += m.z*lk.z + m.w*lk.w;  si += m.w*lk.z - m.z*lk.w;
    }
    float res2 = sqrtf(sr*sr+si*si);
    float fam2 = fminf(fmaxf(res2/(pcb*4.0f),0.f),1.f);
    wgbuf[(long)t*2+1] = sigm(ss*(0.5f-fam2)+sb);
}

// ---------------- M-A: family-fused per-chunk sums (one V pass per family) ----------------
// grid = BB*NC*2(dh)*3(fam), 128 threads
__global__ __launch_bounds__(128) void m_chunksum_fam(
    const float* __restrict__ feat, const float* __restrict__ posph,
    const float* __restrict__ wgbuf, const float* __restrict__ Vbuf,
    const float* __restrict__ lvalbuf, float* __restrict__ cmem)
{
    int blk = blockIdx.x;
    int fam = blk % 3; blk /= 3;
    int dh = blk & 1; blk >>= 1;
    int c = blk % NC; int b = blk / NC;
    int d = dh*128 + threadIdx.x;
    __shared__ __align__(16) float4 kk4[CHK][10];
    __shared__ float gl[CHK];
    long frow = ((long)b*LL + c*CHK)*FS;

    if (fam==0){
        for (int idx=threadIdx.x; idx<CHK*10; idx+=128){
            int t = idx/10, j = idx%10;
            kk4[t][j] = (j<2) ? *(const float4*)&feat[frow + (long)t*FS + JK_OFF + j*4]
                              : *(const float4*)&feat[frow + (long)t*FS + KP_OFF + (j-2)*4];
        }
    } else if (fam==1){
        for (int idx=threadIdx.x; idx<CHK*8; idx+=128){
            int t = idx>>3, j = idx&7;
            kk4[t][j] = *(const float4*)&posph[(long)(c*CHK+t)*32 + j*4];
        }
    } else {
        for (int idx=threadIdx.x; idx<CHK*8; idx+=128){
            int t = idx>>3, j = idx&7;
            kk4[t][j] = *(const float4*)&feat[frow + (long)t*FS + LKP_OFF + j*4];
        }
    }
    for (int t=threadIdx.x; t<CHK; t+=128){
        float gf;
        if (fam==0)      gf = wgbuf[((long)b*LL + c*CHK + t)*2];
        else if (fam==1) gf = 1.0f;
        else             gf = wgbuf[((long)b*LL + c*CHK + t)*2 + 1];
        gl[t] = gf;
    }
    __syncthreads();

    const float* vsrc = (fam==2)? lvalbuf : Vbuf;
    long vrow = ((long)b*LL + c*CHK)*DD + d;

    if (fam==0){
        float cr[20], ci[20];
        #pragma unroll
        for (int i=0;i<20;++i){ cr[i]=0.f; ci[i]=0.f; }
        float vnext = vsrc[vrow];
        for (int t=0;t<CHK;++t){
            float v = vnext * gl[t];
            if (t+1 < CHK) vnext = vsrc[vrow + (long)(t+1)*DD];
            #pragma unroll
            for (int j=0;j<10;++j){
                float4 a = kk4[t][j];
                cr[2*j]   += a.x*v; ci[2*j]   += a.y*v;
                cr[2*j+1] += a.z*v; ci[2*j+1] += a.w*v;
            }
        }
        #pragma unroll
        for (int g5=0; g5<5; ++g5){
            long ob = ((long)(b*NG+g5)*NC + c)*8*DD + d;
            #pragma unroll
            for (int s=0;s<4;++s){
                cmem[ob + (2*s)*DD]   = cr[g5*4+s];
                cmem[ob + (2*s+1)*DD] = ci[g5*4+s];
            }
        }
    } else {
        float cr[16], ci[16];
        #pragma unroll
        for (int i=0;i<16;++i){ cr[i]=0.f; ci[i]=0.f; }
        float vnext = vsrc[vrow];
        for (int t=0;t<CHK;++t){
            float v = vnext * gl[t];
            if (t+1 < CHK) vnext = vsrc[vrow + (long)(t+1)*DD];
            #pragma unroll
            for (int j=0;j<8;++j){
                float4 a = kk4[t][j];
                cr[2*j]   += a.x*v; ci[2*j]   += a.y*v;
                cr[2*j+1] += a.z*v; ci[2*j+1] += a.w*v;
            }
        }
        int g0 = (fam==1)? 5 : 9;
        #pragma unroll
        for (int g=0; g<4; ++g){
            long ob = ((long)(b*NG+g0+g)*NC + c)*8*DD + d;
            #pragma unroll
            for (int s=0;s<4;++s){
                cmem[ob + (2*s)*DD]   = cr[g*4+s];
                cmem[ob + (2*s+1)*DD] = ci[g*4+s];
            }
        }
    }
}

// ---------------- M-B: exclusive scan over chunks (register-resident, re/im split) ----------------
__global__ __launch_bounds__(256) void m_scan(float* __restrict__ cmem){
    int line = blockIdx.x;            // ((b*NG+g)*4 + slot)*2 + comp
    int comp = line & 1; int l2 = line >> 1;
    int lb = l2>>2, slot = l2&3, d = threadIdx.x;
    float v[NC];
    #pragma unroll
    for (int c=0;c<NC;++c){
        long a = ((((long)(lb*NC + c)*4 + slot)*2) + comp)*DD + d;
        v[c] = cmem[a];
    }
    float run = 0.f;
    #pragma unroll
    for (int c=0;c<NC;++c){
        long a = ((((long)(lb*NC + c)*4 + slot)*2) + comp)*DD + d;
        cmem[a] = run;
        run += v[c];
    }
}

// ---------------- M-C: atomic-free per-chunk scan + retrieval ----------------
// grid = BB*NC*2(dh)*2(half); half 0 = cross+banks -> totA; half 1 = pos+ltm -> totB
__global__ __launch_bounds__(128) void m_retrieve2(
    const float* __restrict__ feat, const float* __restrict__ posph,
    const float* __restrict__ wgbuf, const float* __restrict__ Vbuf,
    const float* __restrict__ lvalbuf, const float* __restrict__ cmem,
    const float* __restrict__ set_w, const float* __restrict__ pos_w,
    const float* __restrict__ ltm_w, float* __restrict__ totA, float* __restrict__ totB)
{
    int blk = blockIdx.x;
    int half = blk & 1; blk >>= 1;
    int dh = blk & 1; blk >>= 1;
    int c = blk % NC; int b = blk / NC;
    int d = dh*128 + threadIdx.x;
    __shared__ __align__(16) float4 sA[CHK][8];   // h0: bank k ; h1: posph
    __shared__ __align__(16) float4 sB[CHK][8];   // h0: bank q ; h1: lkp
    __shared__ __align__(16) float4 sC[CHK][4];   // h0: jk(0,1)+jq(2,3)
    __shared__ float sSc[CHK][3];
    long frow = ((long)b*LL + c*CHK)*FS;

    for (int idx=threadIdx.x; idx<CHK*8; idx+=128){
        int t = idx>>3, j = idx&7;
        if (half==0){
            sA[t][j] = *(const float4*)&feat[frow + (long)t*FS + KP_OFF + j*4];
            sB[t][j] = *(const float4*)&feat[frow + (long)t*FS + QP_OFF + j*4];
        } else {
            sA[t][j] = *(const float4*)&posph[(long)(c*CHK+t)*32 + j*4];
            sB[t][j] = *(const float4*)&feat[frow + (long)t*FS + LKP_OFF + j*4];
        }
    }
    if (half==0){
        for (int idx=threadIdx.x; idx<CHK*4; idx+=128){
            int t = idx>>2, j = idx&3;
            sC[t][j] = *(const float4*)&feat[frow + (long)t*FS + JK_OFF + j*4];
        }
    }
    for (int t=threadIdx.x; t<CHK; t+=128){
        int tc = c*CHK + t;
        float gate = feat[frow + (long)t*FS + GATE_OFF];
        if (half==0){
            sSc[t][0] = wgbuf[((long)b*LL+tc)*2];       // bank write gate
            sSc[t][1] = gate*0.2f;                      // output scale
        } else {
            sSc[t][0] = (1.0f-gate)*sigm(pos_w[0]);     // pos scale
            sSc[t][1] = wgbuf[((long)b*LL+tc)*2+1];     // ltm write gate
            sSc[t][2] = sigm(ltm_w[0]) * rsqrtf((float)(tc+1)*16.0f);  // ltm scale
        }
    }
    __syncthreads();

    long vrow = ((long)b*LL + c*CHK)*DD + d;

    if (half == 0){
        float* tp = totA + ((long)b*LL + c*CHK)*DD + d;
        float w0=expf(set_w[0]),w1=expf(set_w[1]),w2=expf(set_w[2]),w3=expf(set_w[3]);
        float den = w0+w1+w2+w3;
        float wn[4] = {w0/den, w1/den, w2/den, w3/den};
        float cr[4], ci[4], br[4][4], bi[4][4];
        #pragma unroll
        for (int s=0;s<4;++s){
            long cb0 = (((long)(b*NG+0)*NC + c)*8 + 2*s)*DD + d;
            cr[s] = cmem[cb0]; ci[s] = cmem[cb0+DD];
        }
        #pragma unroll
        for (int g=0;g<4;++g)
            #pragma unroll
            for (int s=0;s<4;++s){
                long cb = (((long)(b*NG+1+g)*NC + c)*8 + 2*s)*DD + d;
                br[g][s] = cmem[cb]; bi[g][s] = cmem[cb+DD];
            }
        float vnext = Vbuf[vrow];
        #pragma unroll 2
        for (int t=0;t<CHK;++t){
            float v = vnext;
            if (t+1 < CHK) vnext = Vbuf[vrow + (long)(t+1)*DD];
            float vg = v * sSc[t][0];
            float4 jk0 = sC[t][0], jk1 = sC[t][1];
            float4 jq0 = sC[t][2], jq1 = sC[t][3];
            cr[0] += jk0.x*vg; ci[0] += jk0.y*vg;
            cr[1] += jk0.z*vg; ci[1] += jk0.w*vg;
            cr[2] += jk1.x*vg; ci[2] += jk1.y*vg;
            cr[3] += jk1.z*vg; ci[3] += jk1.w*vg;
            float rsc = cr[0]*jq0.x + ci[0]*jq0.y + cr[1]*jq0.z + ci[1]*jq0.w
                      + cr[2]*jq1.x + ci[2]*jq1.y + cr[3]*jq1.z + ci[3]*jq1.w;
            float rbank = 0.f;
            #pragma unroll
            for (int g=0;g<4;++g){
                float4 ka = sA[t][2*g], kb = sA[t][2*g+1];
                float4 qa = sB[t][2*g], qb = sB[t][2*g+1];
                br[g][0] += ka.x*vg; bi[g][0] += ka.y*vg;
                br[g][1] += ka.z*vg; bi[g][1] += ka.w*vg;
                br[g][2] += kb.x*vg; bi[g][2] += kb.y*vg;
                br[g][3] += kb.z*vg; bi[g][3] += kb.w*vg;
                float rg = br[g][0]*qa.x + bi[g][0]*qa.y + br[g][1]*qa.z + bi[g][1]*qa.w
                         + br[g][2]*qb.x + bi[g][2]*qb.y + br[g][3]*qb.z + bi[g][3]*qb.w;
                rbank += rg*wn[g];
            }
            tp[(long)t*DD] = sSc[t][1]*(rsc + rbank);
        }
    } else {
        float* tp = totB + ((long)b*LL + c*CHK)*DD + d;
        float pr[16], pi2[16], lr[16], li[16];
        #pragma unroll
        for (int g=0;g<4;++g)
            #pragma unroll
            for (int s=0;s<4;++s){
                long cb = (((long)(b*NG+5+g)*NC + c)*8 + 2*s)*DD + d;
                pr[g*4+s] = cmem[cb]; pi2[g*4+s] = cmem[cb+DD];
                long cb2 = (((long)(b*NG+9+g)*NC + c)*8 + 2*s)*DD + d;
                lr[g*4+s] = cmem[cb2]; li[g*4+s] = cmem[cb2+DD];
            }
        float vnext = Vbuf[vrow];
        float lvnext = lvalbuf[vrow];
        #pragma unroll 2
        for (int t=0;t<CHK;++t){
            float v = vnext, lv = lvnext;
            if (t+1 < CHK){
                vnext = Vbuf[vrow + (long)(t+1)*DD];
                lvnext = lvalbuf[vrow + (long)(t+1)*DD];
            }
            float vgl = lv * sSc[t][1];
            float rpos = 0.f, rltm = 0.f;
            #pragma unroll
            for (int j=0;j<8;++j){
                float4 pa = sA[t][j];
                pr[2*j]   += pa.x*v; pi2[2*j]   += pa.y*v;
                rpos += pr[2*j]*pa.x + pi2[2*j]*pa.y;
                pr[2*j+1] += pa.z*v; pi2[2*j+1] += pa.w*v;
                rpos += pr[2*j+1]*pa.z + pi2[2*j+1]*pa.w;
                float4 la = sB[t][j];
                lr[2*j]   += la.x*vgl; li[2*j]   += la.y*vgl;
                rltm += lr[2*j]*la.x + li[2*j]*la.y;
                lr[2*j+1] += la.z*vgl; li[2*j+1] += la.w*vgl;
                rltm += lr[2*j+1]*la.z + li[2*j+1]*la.w;
            }
            tp[(long)t*DD] = sSc[t][0]*rpos + sSc[t][2]*rltm;
        }
    }
}

// ---------------- K4: LN (wave-per-row) + MFMA output projection + residual ----------------
// grid = BB*LL/16 = 256 blocks, 256 threads (4 waves); 16-row tile, K=256
__global__ __launch_bounds__(256) void k4_mfma(
    const float* __restrict__ x, const float* __restrict__ totA,
    const float* __restrict__ totB,
    const float* __restrict__ ln_g, const float* __restrict__ ln_b,
    const unsigned short* __restrict__ owt, const float* __restrict__ obv,
    float* __restrict__ out)
{
    __shared__ __align__(16) char smraw[16384];  // tnh[16][256]ush (8KB, swz) + tnl (8KB, swz)
    int tid = threadIdx.x, lane = tid & 63, wv = tid >> 6;
    long base = (long)blockIdx.x * 16;
    int ar = lane & 15, kk = (lane>>4)*8;

    // ---- LN phase: wave wv owns rows 4wv..4wv+3 ----
    #pragma unroll
    for (int r4=0; r4<4; ++r4){
        int row = wv*4 + r4;
        long grow = base + row;
        int tc = (int)(grow % LL);
        float inv = rsqrtf((float)(tc+1)*4.0f);
        float4 ta = ((const float4*)(totA + grow*DD))[lane];
        float4 tb = ((const float4*)(totB + grow*DD))[lane];
        float vals[4] = {(ta.x+tb.x)*inv, (ta.y+tb.y)*inv, (ta.z+tb.z)*inv, (ta.w+tb.w)*inv};
        float s=0.f, s2=0.f;
        #pragma unroll
        for (int k=0;k<4;++k){ s += vals[k]; s2 += vals[k]*vals[k]; }
        #pragma unroll
        for (int o=1;o<64;o<<=1){ s += __shfl_xor(s,o); s2 += __shfl_xor(s2,o); }
        float mu = s/256.f, var = s2/256.f - mu*mu;
        float rstd = rsqrtf(var + 1e-5f);
        unsigned short h4[4], l4[4];
        #pragma unroll
        for (int k=0;k<4;++k){
            float tv = (vals[k]-mu)*rstd*ln_g[lane*4+k] + ln_b[lane*4+k];
            unsigned short h = f2bf(tv);
            h4[k] = h;
            l4[k] = f2bf(tv - bf2f(h));
        }
        int bo = (row*512 + lane*8) ^ ((row&7)<<4);
        *(ushort4*)(smraw + bo)        = *(ushort4*)h4;
        *(ushort4*)(smraw + 8192 + bo) = *(ushort4*)l4;
    }
    __syncthreads();

    // ---- MFMA phase: wave wv owns cols wv*64..wv*64+63 (4 col-tiles) ----
    f32x4 acc[4];
    #pragma unroll
    for (int j=0;j<4;++j) acc[j] = (f32x4){0.f,0.f,0.f,0.f};
    #pragma unroll
    for (int ksb=0; ksb<8; ++ksb){
        int k0 = ksb*32 + kk;
        int bo = (ar*512 + k0*2) ^ ((ar&7)<<4);
        bf16x8 ahh = *reinterpret_cast<const bf16x8*>(smraw + bo);
        bf16x8 all = *reinterpret_cast<const bf16x8*>(smraw + 8192 + bo);
        #pragma unroll
        for (int j=0;j<4;++j){
            long off = (((long)(wv*4 + j)*8 + ksb)*64 + lane)*8;
            bf16x8 bw = *reinterpret_cast<const bf16x8*>(owt + off);
            acc[j] = __builtin_amdgcn_mfma_f32_16x16x32_bf16(ahh, bw, acc[j], 0,0,0);
            acc[j] = __builtin_amdgcn_mfma_f32_16x16x32_bf16(all, bw, acc[j], 0,0,0);
        }
    }

    // ---- epilogue: out = x + acc + ob ----
    int rl0 = (lane>>4)*4;
    #pragma unroll
    for (int j=0;j<4;++j){
        int col = wv*64 + j*16 + ar;
        float bv = obv[col];
        #pragma unroll
        for (int r=0;r<4;++r){
            long grow = base + rl0 + r;
            out[grow*DD + col] = x[grow*DD + col] + acc[j][r] + bv;
        }
    }
}

// ---------------- launch ----------------
extern "C" void kernel_launch(void* const* d_in, const int* in_sizes, int n_in,
                              void* d_out, int out_size, void* d_ws, size_t ws_size,
                              hipStream_t stream)
{
    const float* x    = (const float*)d_in[0];
    const float* kW1  = (const float*)d_in[1];
    const float* kb1  = (const float*)d_in[2];
    const float* kW2  = (const float*)d_in[3];
    const float* kb2  = (const float*)d_in[4];
    const float* qW1  = (const float*)d_in[5];
    const float* qb1  = (const float*)d_in[6];
    const float* qW2  = (const float*)d_in[7];
    const float* qb2  = (const float*)d_in[8];
    const float* vW   = (const float*)d_in[9];
    const float* vb   = (const float*)d_in[10];
    const float* ln_g = (const float*)d_in[11];
    const float* ln_b = (const float*)d_in[12];
    const float* oW   = (const float*)d_in[13];
    const float* ob   = (const float*)d_in[14];
    const float* set_w= (const float*)d_in[15];
    const float* pf   = (const float*)d_in[16];
    const float* pw   = (const float*)d_in[17];
    const float* gW1  = (const float*)d_in[18];
    const float* gb1  = (const float*)d_in[19];
    const float* gW2  = (const float*)d_in[20];
    const float* gb2  = (const float*)d_in[21];
    const float* lW1  = (const float*)d_in[22];
    const float* lb1  = (const float*)d_in[23];
    const float* lW2  = (const float*)d_in[24];
    const float* lb2  = (const float*)d_in[25];
    const float* lvW  = (const float*)d_in[26];
    const float* lvb  = (const float*)d_in[27];
    const float* ss   = (const float*)d_in[28];
    const float* sb   = (const float*)d_in[29];
    const float* lw   = (const float*)d_in[30];
    float* out = (float*)d_out;

    float* ws    = (float*)d_ws;
    float* feat  = ws + FEAT_O;
    float* Vbuf  = ws + V_O;
    float* lval  = ws + LV_O;
    float* posph = ws + PPH_O;
    float* total = ws + TOT_O;
    float* cmem  = ws + CMEM_O;
    float* km    = ws + KM_O;
    float* wgbuf = ws + WGB_O;
    float* tot2  = ws + TOT2_O;
    unsigned short* xh   = (unsigned short*)(ws + XH_O);
    unsigned short* xl   = (unsigned short*)(ws + XL_O);
    unsigned short* wth  = (unsigned short*)(ws + WTH_O);
    unsigned short* wt2h = (unsigned short*)(ws + WT2H_O);
    unsigned short* owt  = (unsigned short*)(ws + OWT_O);

    (void)in_sizes; (void)n_in; (void)out_size; (void)ws_size;

    prep_all <<<512+192+48+8+32, 256, 0, stream>>>(x, kW1,qW1,lW1,vW,lvW,gW1, kW2,qW2,lW2,
                                                   oW, pf, xh, xl, wth, wt2h, owt, posph);
    mlp_fused<<<6*128, 256, 0, stream>>>(xh,xl,wth,wt2h,
                                         kb1,kb2, qb1,qb2, lb1,lb2,
                                         vb,lvb, gb1,gW2,gb2, feat, Vbuf, lval);
    g_prefix4<<<BB*10, 256, 0, stream>>>(feat, km);
    g_fam    <<<(BB*LL)/64, 64, 0, stream>>>(feat, km, ss, sb, wgbuf);
    m_chunksum_fam <<<BB*NC*2*3, 128, 0, stream>>>(feat, posph, wgbuf, Vbuf, lval, cmem);
    m_scan     <<<BB*NG*4*2, 256, 0, stream>>>(cmem);
    m_retrieve2 <<<BB*NC*2*2, 128, 0, stream>>>(feat, posph, wgbuf, Vbuf, lval, cmem,
                                                set_w, pw, lw, total, tot2);
    k4_mfma    <<<BB*LL/16, 256, 0, stream>>>(x, total, tot2, ln_g, ln_b, owt, ob, out);
}

// Round 13
// 99.912 us; speedup vs baseline: 1.1119x; 1.1119x over previous
//
#include <hip/hip_runtime.h>
#include <math.h>

// ---------------- problem constants ----------------
#define DD   256
#define NSB  4
#define PPB  4
#define POSB 16
#define LL   2048
#define BB   2
#define NC   128        // time chunks
#define CHK  16         // LL/NC
#define NG   13         // groups: 0=cross, 1-4 banks, 5-8 pos, 9-12 ltm (4 complex slots each)
#define FS   128        // feature row stride (floats)
#define PI_F 3.14159265358979323846f

// feature row offsets (floats)
#define JK_OFF   0
#define JQ_OFF   8
#define KP_OFF   16
#define QP_OFF   48
#define LKP_OFF  80
#define GATE_OFF 112

// workspace layout (float offsets) — ws_size is ~256 MiB, plenty
#define FEAT_O  0L
#define V_O     524288L                  // BB*LL*FS
#define LV_O    1572864L                 // V_O + BB*LL*DD
#define PPH_O   2621440L                 // LV_O + BB*LL*DD
#define TOT_O   2686976L                 // PPH_O + LL*32
#define CMEM_O  3735552L                 // TOT_O + BB*LL*DD ; size BB*NG*NC*8*DD = 6815744
#define WGB_O   10551296L                // CMEM_O + 6815744
#define TOT2_O  10559488L                // WGB_O + BB*LL*2
#define OWT_O   11608064L                // TOT2_O + BB*LL*DD
#define WS_FLOATS 11640832L              // (~46.6 MB)
// aliases inside the CMEM region (all dead before m_chunksum writes cmem):
#define KM_O    CMEM_O                   // g_prefix output, BB*LL*40 = 163840 floats
#define XH_O    CMEM_O                   // prep buffers, consumed by mlp_fused
#define XL_O    (CMEM_O + 524288L)
#define WTH_O   (CMEM_O + 1048576L)      // 96*8*64*8 ushort = 196608 floats
#define WT2H_O  (CMEM_O + 1245184L)      // 3*16*256 ushort = 6144 floats; end 1251328 <= 6815744

typedef __attribute__((ext_vector_type(8))) short bf16x8;
typedef __attribute__((ext_vector_type(4))) float f32x4;

__device__ __forceinline__ float sigm(float v){ return 1.0f/(1.0f+expf(-v)); }
__device__ __forceinline__ float gelu_exact(float v){ return 0.5f*v*(1.0f+erff(v*0.70710678118654752f)); }
__device__ __forceinline__ unsigned short f2bf(float f){
    unsigned u = __float_as_uint(f);
    unsigned r = u + 0x7fffu + ((u>>16)&1u);
    return (unsigned short)(r>>16);
}
__device__ __forceinline__ float bf2f(unsigned short h){ return __uint_as_float(((unsigned)h)<<16); }

// ---------------- PREP (merged): fragment-packed x / W1 / W2 / oW / pos phasors ----------------
// grid = 512 (x) + 192 (W1) + 48 (W2) + 8 (posph) + 32 (oW) = 792
__global__ __launch_bounds__(256) void prep_all(
    const float* __restrict__ x,
    const float* __restrict__ kW1, const float* __restrict__ qW1, const float* __restrict__ lW1,
    const float* __restrict__ vW,  const float* __restrict__ lvW, const float* __restrict__ gW1,
    const float* __restrict__ kW2, const float* __restrict__ qW2, const float* __restrict__ lW2,
    const float* __restrict__ oW,  const float* __restrict__ pf,
    unsigned short* __restrict__ xh, unsigned short* __restrict__ xl,
    unsigned short* __restrict__ wth, unsigned short* __restrict__ wt2h,
    unsigned short* __restrict__ owt, float* __restrict__ posph)
{
    int bid = blockIdx.x, tid = threadIdx.x;
    if (bid < 512){
        int gid = bid*256 + tid;          // (4096/16)*8*64
        int frag = gid>>6, lane = gid&63;
        int tile = frag>>3, ksb = frag&7;
        int row = tile*16 + (lane&15);
        int k0  = ksb*32 + ((lane>>4)&3)*8;
        const float* xp = x + (long)row*DD + k0;
        unsigned short h8[8], l8[8];
        #pragma unroll
        for (int e=0;e<8;++e){
            float f = xp[e];
            unsigned short h = f2bf(f);
            h8[e] = h;
            l8[e] = f2bf(f - bf2f(h));
        }
        *(bf16x8*)(xh + (long)gid*8) = *(bf16x8*)h8;
        *(bf16x8*)(xl + (long)gid*8) = *(bf16x8*)l8;
    } else if (bid < 512+192){
        int gid = (bid-512)*256 + tid;    // 96*8*64
        int frag = gid>>6, lane = gid&63;
        int tile = frag>>3, ksb = frag&7;
        int col = tile*16 + (lane&15);
        int k0  = ksb*32 + ((lane>>4)&3)*8;
        unsigned short h8[8];
        #pragma unroll
        for (int e=0;e<8;++e){
            int fi = k0 + e;
            float w = 0.f;
            if (col < 1408){
                int m = col >> 8;
                if (m < 5){
                    const float* W = (m==0)?kW1:((m==1)?qW1:((m==2)?lW1:((m==3)?vW:lvW)));
                    w = W[(long)fi*DD + (col & 255)];
                } else {
                    w = gW1[(long)fi*128 + (col - 1280)];
                }
            }
            h8[e] = f2bf(w);
        }
        *(bf16x8*)(wth + (long)gid*8) = *(bf16x8*)h8;
    } else if (bid < 512+192+48){
        int blk = bid - (512+192);
        int m = blk>>4, o = blk&15;
        const float* W2 = (m==0)?kW2:((m==1)?qW2:lW2);
        wt2h[(long)blk*DD + tid] = f2bf(W2[tid*16+o]);
    } else if (bid < 512+192+48+8){
        int t = (bid - (512+192+48))*256 + tid;
        if (t < LL){
            #pragma unroll
            for (int j=0;j<POSB;++j){
                float ang = (((float)t * pf[j]) * 2.0f) * PI_F;
                float s,c; sincosf(ang,&s,&c);
                posph[t*32+2*j]   = c;
                posph[t*32+2*j+1] = s;
            }
        }
    } else {
        // ---- oW^T fragment-packed (hi only): 128 frags x 64 lanes ----
        int gid = (bid - (512+192+48+8))*256 + tid;   // 0..8191
        int frag = gid>>6, lane = gid&63;
        int tile = frag>>3, ksb = frag&7;
        int col = tile*16 + (lane&15);
        int k0  = ksb*32 + ((lane>>4)&3)*8;
        unsigned short h8[8];
        #pragma unroll
        for (int e=0;e<8;++e)
            h8[e] = f2bf(oW[(long)(k0+e)*DD + col]);
        *(bf16x8*)(owt + (long)gid*8) = *(bf16x8*)h8;
    }
}

// ---------------- MLP fused: MFMA GEMM (32-row tiles, packed coalesced loads, 1-deep) ----------------
__global__ __launch_bounds__(256) void mlp_fused(
    const unsigned short* __restrict__ xh, const unsigned short* __restrict__ xl,
    const unsigned short* __restrict__ wth, const unsigned short* __restrict__ wt2h,
    const float* __restrict__ kb1, const float* __restrict__ kb2,
    const float* __restrict__ qb1, const float* __restrict__ qb2,
    const float* __restrict__ lb1, const float* __restrict__ lb2,
    const float* __restrict__ vb,  const float* __restrict__ lvb,
    const float* __restrict__ gb1, const float* __restrict__ gW2, const float* __restrict__ gb2,
    float* __restrict__ feat, float* __restrict__ Vbuf, float* __restrict__ lvalbuf)
{
    __shared__ __align__(16) char smraw[18432];
    int tid = threadIdx.x, lane = tid & 63, wv = tid >> 6;
    int mat = blockIdx.x >> 7, bm = blockIdx.x & 127;
    int rowg0 = bm*32;
    int ar = lane & 15, kk = (lane>>4)*8;

    f32x4 acc[2][4];
    #pragma unroll
    for (int i=0;i<2;++i)
        #pragma unroll
        for (int j=0;j<4;++j) acc[i][j] = (f32x4){0.f,0.f,0.f,0.f};

    bf16x8 ah[2], al[2], bh[4];
    {
        #pragma unroll
        for (int i=0;i<2;++i){
            long off = (((long)(2*bm+i)*8 + 0)*64 + lane)*8;
            ah[i] = *reinterpret_cast<const bf16x8*>(xh + off);
            al[i] = *reinterpret_cast<const bf16x8*>(xl + off);
        }
        #pragma unroll
        for (int j=0;j<4;++j){
            long off = (((long)(mat*16 + wv*4 + j)*8 + 0)*64 + lane)*8;
            bh[j] = *reinterpret_cast<const bf16x8*>(wth + off);
        }
    }
    #pragma unroll
    for (int ksb=0; ksb<8; ++ksb){
        bf16x8 nah[2], nal[2], nbh[4];
        if (ksb < 7){
            #pragma unroll
            for (int i=0;i<2;++i){
                long off = (((long)(2*bm+i)*8 + ksb+1)*64 + lane)*8;
                nah[i] = *reinterpret_cast<const bf16x8*>(xh + off);
                nal[i] = *reinterpret_cast<const bf16x8*>(xl + off);
            }
            #pragma unroll
            for (int j=0;j<4;++j){
                long off = (((long)(mat*16 + wv*4 + j)*8 + ksb+1)*64 + lane)*8;
                nbh[j] = *reinterpret_cast<const bf16x8*>(wth + off);
            }
        }
        #pragma unroll
        for (int i=0;i<2;++i)
            #pragma unroll
            for (int j=0;j<4;++j){
                acc[i][j] = __builtin_amdgcn_mfma_f32_16x16x32_bf16(ah[i], bh[j], acc[i][j], 0,0,0);
                acc[i][j] = __builtin_amdgcn_mfma_f32_16x16x32_bf16(al[i], bh[j], acc[i][j], 0,0,0);
            }
        if (ksb < 7){
            #pragma unroll
            for (int i=0;i<2;++i){ ah[i]=nah[i]; al[i]=nal[i]; }
            #pragma unroll
            for (int j=0;j<4;++j) bh[j]=nbh[j];
        }
    }

    int rl0 = (lane>>4)*4;

    if (mat < 3){
        float (*ang)[16] = (float(*)[16])(smraw + 16384);
        const float* b1 = (mat==0)?kb1:((mat==1)?qb1:lb1);
        #pragma unroll
        for (int i=0;i<2;++i)
            #pragma unroll
            for (int j=0;j<4;++j){
                int c = wv*64 + j*16 + ar;
                #pragma unroll
                for (int r=0;r<4;++r){
                    int row = i*16 + rl0 + r;
                    float hv = gelu_exact(acc[i][j][r] + b1[c]);
                    int bo = row*512 + c*2;
                    *(unsigned short*)(smraw + (bo ^ ((row&7)<<4))) = f2bf(hv);
                }
            }
        __syncthreads();
        const float* b2 = (mat==0)?kb2:((mat==1)?qb2:lb2);
        int off = (mat==0)?KP_OFF:((mat==1)?QP_OFF:LKP_OFF);
        if (wv < 2){
            int arow = wv*16 + ar;
            f32x4 a2 = (f32x4){0.f,0.f,0.f,0.f};
            #pragma unroll
            for (int ksb=0; ksb<8; ++ksb){
                int k = ksb*32 + kk;
                int bo = arow*512 + k*2;
                bf16x8 af = *reinterpret_cast<const bf16x8*>(smraw + (bo ^ ((arow&7)<<4)));
                bf16x8 bf = *reinterpret_cast<const bf16x8*>(wt2h + ((long)(mat*16 + ar)*DD + k));
                a2 = __builtin_amdgcn_mfma_f32_16x16x32_bf16(af, bf, a2, 0,0,0);
            }
            int o = ar;
            #pragma unroll
            for (int r=0;r<4;++r){
                int tok = wv*16 + rl0 + r;
                float a = tanhf(a2[r] + b2[o])*PI_F;
                ang[tok][o] = a;
                float sn,cs; sincosf(a,&sn,&cs);
                long rowg = rowg0 + tok;
                feat[rowg*FS + off + 2*o]   = cs;
                feat[rowg*FS + off + 2*o+1] = sn;
            }
        }
        __syncthreads();
        if (mat<2 && tid<128){
            int tok = tid>>2, p = tid&3;
            float a = ang[tok][p]+ang[tok][4+p]+ang[tok][8+p]+ang[tok][12+p];
            float sn,cs; sincosf(a,&sn,&cs);
            int joff = (mat==0)?JK_OFF:JQ_OFF;
            long rowg = rowg0 + tok;
            feat[rowg*FS + joff + 2*p]   = cs;
            feat[rowg*FS + joff + 2*p+1] = sn;
        }
    } else if (mat < 5){
        const float* bv = (mat==3)? vb : lvb;
        float* dst = (mat==3)? Vbuf : lvalbuf;
        #pragma unroll
        for (int i=0;i<2;++i)
            #pragma unroll
            for (int j=0;j<4;++j){
                int c = wv*64 + j*16 + ar;
                #pragma unroll
                for (int r=0;r<4;++r)
                    dst[(long)(rowg0 + i*16 + rl0 + r)*DD + c] = acc[i][j][r] + bv[c];
            }
    } else {
        float (*hg)[132] = (float(*)[132])smraw;
        float (*part)[8] = (float(*)[8])(smraw + 32*132*4);
        if (wv < 2){
            #pragma unroll
            for (int i=0;i<2;++i)
                #pragma unroll
                for (int j=0;j<4;++j){
                    int c = wv*64 + j*16 + ar;
                    #pragma unroll
                    for (int r=0;r<4;++r)
                        hg[i*16 + rl0 + r][c] = gelu_exact(acc[i][j][r] + gb1[c]);
                }
        }
        __syncthreads();
        {
            int tok = tid>>3, jj = tid&7;
            float s = 0.f;
            #pragma unroll
            for (int c=0;c<16;++c) s += hg[tok][jj*16+c]*gW2[jj*16+c];
            part[tok][jj] = s;
        }
        __syncthreads();
        if (tid < 32){
            float s = gb2[0];
            #pragma unroll
            for (int j=0;j<8;++j) s += part[tid][j];
            feat[(long)(rowg0+tid)*FS + GATE_OFF] = sigm(s);
        }
    }
}

// ---------------- G-A: float4 exclusive prefix of 10 channel-quads ----------------
__global__ __launch_bounds__(256) void g_prefix4(const float* __restrict__ feat, float* __restrict__ km){
    int b = blockIdx.x / 10, q = blockIdx.x % 10;
    int off = (q<2) ? (JK_OFF + q*4) : (LKP_OFF + (q-2)*4);
    int tid = threadIdx.x;
    long rb = (long)b*LL*FS;
    float4 v[8]; float4 s = {0.f,0.f,0.f,0.f};
    #pragma unroll
    for (int u=0;u<8;++u){
        v[u] = *(const float4*)&feat[rb + (long)(tid*8+u)*FS + off];
        s.x += v[u].x; s.y += v[u].y; s.z += v[u].z; s.w += v[u].w;
    }
    int lane = tid & 63, w = tid >> 6;
    float4 xs = s;
    #pragma unroll
    for (int o=1;o<64;o<<=1){
        float yx = __shfl_up(xs.x,o), yy = __shfl_up(xs.y,o);
        float yz = __shfl_up(xs.z,o), yw = __shfl_up(xs.w,o);
        if (lane>=o){ xs.x += yx; xs.y += yy; xs.z += yz; xs.w += yw; }
    }
    __shared__ float4 wsum[4];
    if (lane==63) wsum[w] = xs;
    __syncthreads();
    float4 woff = {0.f,0.f,0.f,0.f};
    for (int i=0;i<w;++i){
        woff.x += wsum[i].x; woff.y += wsum[i].y; woff.z += wsum[i].z; woff.w += wsum[i].w;
    }
    float4 run = {xs.x - s.x + woff.x, xs.y - s.y + woff.y,
                  xs.z - s.z + woff.z, xs.w - s.w + woff.w};
    #pragma unroll
    for (int u=0;u<8;++u){
        *(float4*)&km[((long)b*LL + tid*8+u)*40 + q*4] = run;
        run.x += v[u].x; run.y += v[u].y; run.z += v[u].z; run.w += v[u].w;
    }
}

// ---------------- G-B: per-token familiarity + write gates (float4) ----------------
__global__ __launch_bounds__(64) void g_fam(
    const float* __restrict__ feat, const float* __restrict__ km,
    const float* __restrict__ ss_p, const float* __restrict__ sb_p,
    float* __restrict__ wgbuf)
{
    int t = blockIdx.x*64 + threadIdx.x;
    if (t >= BB*LL) return;
    int tc = t % LL;
    float ss = ss_p[0], sb = sb_p[0];
    long frow = (long)t*FS;
    const float* kmrow = km + (long)t*40;
    float pcb = fmaxf((float)tc, 1.0f);

    float sr=0.f, si=0.f;
    #pragma unroll
    for (int h=0;h<2;++h){
        float4 jk = *(const float4*)&feat[frow+JK_OFF+h*4];
        float4 m  = *(const float4*)&kmrow[h*4];
        sr += m.x*jk.x + m.y*jk.y;  si += m.y*jk.x - m.x*jk.y;
        sr += m.z*jk.z + m.w*jk.w;  si += m.w*jk.z - m.z*jk.w;
    }
    float res = sqrtf(sr*sr+si*si);
    float fam = fminf(fmaxf(res/(pcb*2.0f),0.f),1.f);
    wgbuf[(long)t*2] = sigm(ss*(0.5f-fam)+sb);

    sr=0.f; si=0.f;
    #pragma unroll
    for (int h=0;h<8;++h){
        float4 lk = *(const float4*)&feat[frow+LKP_OFF+h*4];
        float4 m  = *(const float4*)&kmrow[8+h*4];
        sr += m.x*lk.x + m.y*lk.y;  si += m.y*lk.x - m.x*lk.y;
        sr += m.z*lk.z + m.w*lk.w;  si += m.w*lk.z - m.z*lk.w;
    }
    float res2 = sqrtf(sr*sr+si*si);
    float fam2 = fminf(fmaxf(res2/(pcb*4.0f),0.f),1.f);
    wgbuf[(long)t*2+1] = sigm(ss*(0.5f-fam2)+sb);
}

// ---------------- M-A: family-fused per-chunk sums (one V pass per family) ----------------
// grid = BB*NC*2(dh)*3(fam), 128 threads
__global__ __launch_bounds__(128) void m_chunksum_fam(
    const float* __restrict__ feat, const float* __restrict__ posph,
    const float* __restrict__ wgbuf, const float* __restrict__ Vbuf,
    const float* __restrict__ lvalbuf, float* __restrict__ cmem)
{
    int blk = blockIdx.x;
    int fam = blk % 3; blk /= 3;
    int dh = blk & 1; blk >>= 1;
    int c = blk % NC; int b = blk / NC;
    int d = dh*128 + threadIdx.x;
    __shared__ __align__(16) float4 kk4[CHK][10];
    __shared__ float gl[CHK];
    long frow = ((long)b*LL + c*CHK)*FS;

    if (fam==0){
        for (int idx=threadIdx.x; idx<CHK*10; idx+=128){
            int t = idx/10, j = idx%10;
            kk4[t][j] = (j<2) ? *(const float4*)&feat[frow + (long)t*FS + JK_OFF + j*4]
                              : *(const float4*)&feat[frow + (long)t*FS + KP_OFF + (j-2)*4];
        }
    } else if (fam==1){
        for (int idx=threadIdx.x; idx<CHK*8; idx+=128){
            int t = idx>>3, j = idx&7;
            kk4[t][j] = *(const float4*)&posph[(long)(c*CHK+t)*32 + j*4];
        }
    } else {
        for (int idx=threadIdx.x; idx<CHK*8; idx+=128){
            int t = idx>>3, j = idx&7;
            kk4[t][j] = *(const float4*)&feat[frow + (long)t*FS + LKP_OFF + j*4];
        }
    }
    for (int t=threadIdx.x; t<CHK; t+=128){
        float gf;
        if (fam==0)      gf = wgbuf[((long)b*LL + c*CHK + t)*2];
        else if (fam==1) gf = 1.0f;
        else             gf = wgbuf[((long)b*LL + c*CHK + t)*2 + 1];
        gl[t] = gf;
    }
    __syncthreads();

    const float* vsrc = (fam==2)? lvalbuf : Vbuf;
    long vrow = ((long)b*LL + c*CHK)*DD + d;

    if (fam==0){
        float cr[20], ci[20];
        #pragma unroll
        for (int i=0;i<20;++i){ cr[i]=0.f; ci[i]=0.f; }
        float vnext = vsrc[vrow];
        for (int t=0;t<CHK;++t){
            float v = vnext * gl[t];
            if (t+1 < CHK) vnext = vsrc[vrow + (long)(t+1)*DD];
            #pragma unroll
            for (int j=0;j<10;++j){
                float4 a = kk4[t][j];
                cr[2*j]   += a.x*v; ci[2*j]   += a.y*v;
                cr[2*j+1] += a.z*v; ci[2*j+1] += a.w*v;
            }
        }
        #pragma unroll
        for (int g5=0; g5<5; ++g5){
            long ob = ((long)(b*NG+g5)*NC + c)*8*DD + d;
            #pragma unroll
            for (int s=0;s<4;++s){
                cmem[ob + (2*s)*DD]   = cr[g5*4+s];
                cmem[ob + (2*s+1)*DD] = ci[g5*4+s];
            }
        }
    } else {
        float cr[16], ci[16];
        #pragma unroll
        for (int i=0;i<16;++i){ cr[i]=0.f; ci[i]=0.f; }
        float vnext = vsrc[vrow];
        for (int t=0;t<CHK;++t){
            float v = vnext * gl[t];
            if (t+1 < CHK) vnext = vsrc[vrow + (long)(t+1)*DD];
            #pragma unroll
            for (int j=0;j<8;++j){
                float4 a = kk4[t][j];
                cr[2*j]   += a.x*v; ci[2*j]   += a.y*v;
                cr[2*j+1] += a.z*v; ci[2*j+1] += a.w*v;
            }
        }
        int g0 = (fam==1)? 5 : 9;
        #pragma unroll
        for (int g=0; g<4; ++g){
            long ob = ((long)(b*NG+g0+g)*NC + c)*8*DD + d;
            #pragma unroll
            for (int s=0;s<4;++s){
                cmem[ob + (2*s)*DD]   = cr[g*4+s];
                cmem[ob + (2*s+1)*DD] = ci[g*4+s];
            }
        }
    }
}

// ---------------- M-B: exclusive scan over chunks (two 64-reg passes, re/im split) ----------------
__global__ __launch_bounds__(256) void m_scan(float* __restrict__ cmem){
    int line = blockIdx.x;            // ((b*NG+g)*4 + slot)*2 + comp
    int comp = line & 1; int l2 = line >> 1;
    int lb = l2>>2, slot = l2&3, d = threadIdx.x;
    float run = 0.f;
    for (int h=0; h<2; ++h){
        float v[NC/2];
        #pragma unroll
        for (int c=0;c<NC/2;++c){
            long a = ((((long)(lb*NC + h*(NC/2) + c)*4 + slot)*2) + comp)*DD + d;
            v[c] = cmem[a];
        }
        #pragma unroll
        for (int c=0;c<NC/2;++c){
            long a = ((((long)(lb*NC + h*(NC/2) + c)*4 + slot)*2) + comp)*DD + d;
            cmem[a] = run;
            run += v[c];
        }
    }
}

// ---------------- M-C: atomic-free per-chunk scan + retrieval ----------------
// grid = BB*NC*2(dh)*2(half); half 0 = cross+banks -> totA; half 1 = pos+ltm -> totB
__global__ __launch_bounds__(128) void m_retrieve2(
    const float* __restrict__ feat, const float* __restrict__ posph,
    const float* __restrict__ wgbuf, const float* __restrict__ Vbuf,
    const float* __restrict__ lvalbuf, const float* __restrict__ cmem,
    const float* __restrict__ set_w, const float* __restrict__ pos_w,
    const float* __restrict__ ltm_w, float* __restrict__ totA, float* __restrict__ totB)
{
    int blk = blockIdx.x;
    int half = blk & 1; blk >>= 1;
    int dh = blk & 1; blk >>= 1;
    int c = blk % NC; int b = blk / NC;
    int d = dh*128 + threadIdx.x;
    __shared__ __align__(16) float4 sA[CHK][8];   // h0: bank k ; h1: posph
    __shared__ __align__(16) float4 sB[CHK][8];   // h0: bank q ; h1: lkp
    __shared__ __align__(16) float4 sC[CHK][4];   // h0: jk(0,1)+jq(2,3)
    __shared__ float sSc[CHK][3];
    long frow = ((long)b*LL + c*CHK)*FS;

    for (int idx=threadIdx.x; idx<CHK*8; idx+=128){
        int t = idx>>3, j = idx&7;
        if (half==0){
            sA[t][j] = *(const float4*)&feat[frow + (long)t*FS + KP_OFF + j*4];
            sB[t][j] = *(const float4*)&feat[frow + (long)t*FS + QP_OFF + j*4];
        } else {
            sA[t][j] = *(const float4*)&posph[(long)(c*CHK+t)*32 + j*4];
            sB[t][j] = *(const float4*)&feat[frow + (long)t*FS + LKP_OFF + j*4];
        }
    }
    if (half==0){
        for (int idx=threadIdx.x; idx<CHK*4; idx+=128){
            int t = idx>>2, j = idx&3;
            sC[t][j] = *(const float4*)&feat[frow + (long)t*FS + JK_OFF + j*4];
        }
    }
    for (int t=threadIdx.x; t<CHK; t+=128){
        int tc = c*CHK + t;
        float gate = feat[frow + (long)t*FS + GATE_OFF];
        if (half==0){
            sSc[t][0] = wgbuf[((long)b*LL+tc)*2];       // bank write gate
            sSc[t][1] = gate*0.2f;                      // output scale
        } else {
            sSc[t][0] = (1.0f-gate)*sigm(pos_w[0]);     // pos scale
            sSc[t][1] = wgbuf[((long)b*LL+tc)*2+1];     // ltm write gate
            sSc[t][2] = sigm(ltm_w[0]) * rsqrtf((float)(tc+1)*16.0f);  // ltm scale
        }
    }
    __syncthreads();

    long vrow = ((long)b*LL + c*CHK)*DD + d;

    if (half == 0){
        float* tp = totA + ((long)b*LL + c*CHK)*DD + d;
        float w0=expf(set_w[0]),w1=expf(set_w[1]),w2=expf(set_w[2]),w3=expf(set_w[3]);
        float den = w0+w1+w2+w3;
        float wn[4] = {w0/den, w1/den, w2/den, w3/den};
        float cr[4], ci[4], br[4][4], bi[4][4];
        #pragma unroll
        for (int s=0;s<4;++s){
            long cb0 = (((long)(b*NG+0)*NC + c)*8 + 2*s)*DD + d;
            cr[s] = cmem[cb0]; ci[s] = cmem[cb0+DD];
        }
        #pragma unroll
        for (int g=0;g<4;++g)
            #pragma unroll
            for (int s=0;s<4;++s){
                long cb = (((long)(b*NG+1+g)*NC + c)*8 + 2*s)*DD + d;
                br[g][s] = cmem[cb]; bi[g][s] = cmem[cb+DD];
            }
        float vnext = Vbuf[vrow];
        #pragma unroll 2
        for (int t=0;t<CHK;++t){
            float v = vnext;
            if (t+1 < CHK) vnext = Vbuf[vrow + (long)(t+1)*DD];
            float vg = v * sSc[t][0];
            float4 jk0 = sC[t][0], jk1 = sC[t][1];
            float4 jq0 = sC[t][2], jq1 = sC[t][3];
            cr[0] += jk0.x*vg; ci[0] += jk0.y*vg;
            cr[1] += jk0.z*vg; ci[1] += jk0.w*vg;
            cr[2] += jk1.x*vg; ci[2] += jk1.y*vg;
            cr[3] += jk1.z*vg; ci[3] += jk1.w*vg;
            float rsc = cr[0]*jq0.x + ci[0]*jq0.y + cr[1]*jq0.z + ci[1]*jq0.w
                      + cr[2]*jq1.x + ci[2]*jq1.y + cr[3]*jq1.z + ci[3]*jq1.w;
            float rbank = 0.f;
            #pragma unroll
            for (int g=0;g<4;++g){
                float4 ka = sA[t][2*g], kb = sA[t][2*g+1];
                float4 qa = sB[t][2*g], qb = sB[t][2*g+1];
                br[g][0] += ka.x*vg; bi[g][0] += ka.y*vg;
                br[g][1] += ka.z*vg; bi[g][1] += ka.w*vg;
                br[g][2] += kb.x*vg; bi[g][2] += kb.y*vg;
                br[g][3] += kb.z*vg; bi[g][3] += kb.w*vg;
                float rg = br[g][0]*qa.x + bi[g][0]*qa.y + br[g][1]*qa.z + bi[g][1]*qa.w
                         + br[g][2]*qb.x + bi[g][2]*qb.y + br[g][3]*qb.z + bi[g][3]*qb.w;
                rbank += rg*wn[g];
            }
            tp[(long)t*DD] = sSc[t][1]*(rsc + rbank);
        }
    } else {
        float* tp = totB + ((long)b*LL + c*CHK)*DD + d;
        float pr[16], pi2[16], lr[16], li[16];
        #pragma unroll
        for (int g=0;g<4;++g)
            #pragma unroll
            for (int s=0;s<4;++s){
                long cb = (((long)(b*NG+5+g)*NC + c)*8 + 2*s)*DD + d;
                pr[g*4+s] = cmem[cb]; pi2[g*4+s] = cmem[cb+DD];
                long cb2 = (((long)(b*NG+9+g)*NC + c)*8 + 2*s)*DD + d;
                lr[g*4+s] = cmem[cb2]; li[g*4+s] = cmem[cb2+DD];
            }
        float vnext = Vbuf[vrow];
        float lvnext = lvalbuf[vrow];
        #pragma unroll 2
        for (int t=0;t<CHK;++t){
            float v = vnext, lv = lvnext;
            if (t+1 < CHK){
                vnext = Vbuf[vrow + (long)(t+1)*DD];
                lvnext = lvalbuf[vrow + (long)(t+1)*DD];
            }
            float vgl = lv * sSc[t][1];
            float rpos = 0.f, rltm = 0.f;
            #pragma unroll
            for (int j=0;j<8;++j){
                float4 pa = sA[t][j];
                pr[2*j]   += pa.x*v; pi2[2*j]   += pa.y*v;
                rpos += pr[2*j]*pa.x + pi2[2*j]*pa.y;
                pr[2*j+1] += pa.z*v; pi2[2*j+1] += pa.w*v;
                rpos += pr[2*j+1]*pa.z + pi2[2*j+1]*pa.w;
                float4 la = sB[t][j];
                lr[2*j]   += la.x*vgl; li[2*j]   += la.y*vgl;
                rltm += lr[2*j]*la.x + li[2*j]*la.y;
                lr[2*j+1] += la.z*vgl; li[2*j+1] += la.w*vgl;
                rltm += lr[2*j+1]*la.z + li[2*j+1]*la.w;
            }
            tp[(long)t*DD] = sSc[t][0]*rpos + sSc[t][2]*rltm;
        }
    }
}

// ---------------- K4: LN (wave-per-row) + MFMA output projection + residual ----------------
// grid = BB*LL/16 = 256 blocks, 256 threads (4 waves); 16-row tile, K=256
__global__ __launch_bounds__(256) void k4_mfma(
    const float* __restrict__ x, const float* __restrict__ totA,
    const float* __restrict__ totB,
    const float* __restrict__ ln_g, const float* __restrict__ ln_b,
    const unsigned short* __restrict__ owt, const float* __restrict__ obv,
    float* __restrict__ out)
{
    __shared__ __align__(16) char smraw[16384];  // tnh[16][256]ush (8KB, swz) + tnl (8KB, swz)
    int tid = threadIdx.x, lane = tid & 63, wv = tid >> 6;
    long base = (long)blockIdx.x * 16;
    int ar = lane & 15, kk = (lane>>4)*8;

    // ---- LN phase: wave wv owns rows 4wv..4wv+3 ----
    #pragma unroll
    for (int r4=0; r4<4; ++r4){
        int row = wv*4 + r4;
        long grow = base + row;
        int tc = (int)(grow % LL);
        float inv = rsqrtf((float)(tc+1)*4.0f);
        float4 ta = ((const float4*)(totA + grow*DD))[lane];
        float4 tb = ((const float4*)(totB + grow*DD))[lane];
        float vals[4] = {(ta.x+tb.x)*inv, (ta.y+tb.y)*inv, (ta.z+tb.z)*inv, (ta.w+tb.w)*inv};
        float s=0.f, s2=0.f;
        #pragma unroll
        for (int k=0;k<4;++k){ s += vals[k]; s2 += vals[k]*vals[k]; }
        #pragma unroll
        for (int o=1;o<64;o<<=1){ s += __shfl_xor(s,o); s2 += __shfl_xor(s2,o); }
        float mu = s/256.f, var = s2/256.f - mu*mu;
        float rstd = rsqrtf(var + 1e-5f);
        unsigned short h4[4], l4[4];
        #pragma unroll
        for (int k=0;k<4;++k){
            float tv = (vals[k]-mu)*rstd*ln_g[lane*4+k] + ln_b[lane*4+k];
            unsigned short h = f2bf(tv);
            h4[k] = h;
            l4[k] = f2bf(tv - bf2f(h));
        }
        int bo = (row*512 + lane*8) ^ ((row&7)<<4);
        *(ushort4*)(smraw + bo)        = *(ushort4*)h4;
        *(ushort4*)(smraw + 8192 + bo) = *(ushort4*)l4;
    }
    __syncthreads();

    // ---- MFMA phase: wave wv owns cols wv*64..wv*64+63 (4 col-tiles) ----
    f32x4 acc[4];
    #pragma unroll
    for (int j=0;j<4;++j) acc[j] = (f32x4){0.f,0.f,0.f,0.f};
    #pragma unroll
    for (int ksb=0; ksb<8; ++ksb){
        int k0 = ksb*32 + kk;
        int bo = (ar*512 + k0*2) ^ ((ar&7)<<4);
        bf16x8 ahh = *reinterpret_cast<const bf16x8*>(smraw + bo);
        bf16x8 all = *reinterpret_cast<const bf16x8*>(smraw + 8192 + bo);
        #pragma unroll
        for (int j=0;j<4;++j){
            long off = (((long)(wv*4 + j)*8 + ksb)*64 + lane)*8;
            bf16x8 bw = *reinterpret_cast<const bf16x8*>(owt + off);
            acc[j] = __builtin_amdgcn_mfma_f32_16x16x32_bf16(ahh, bw, acc[j], 0,0,0);
            acc[j] = __builtin_amdgcn_mfma_f32_16x16x32_bf16(all, bw, acc[j], 0,0,0);
        }
    }

    // ---- epilogue: out = x + acc + ob ----
    int rl0 = (lane>>4)*4;
    #pragma unroll
    for (int j=0;j<4;++j){
        int col = wv*64 + j*16 + ar;
        float bv = obv[col];
        #pragma unroll
        for (int r=0;r<4;++r){
            long grow = base + rl0 + r;
            out[grow*DD + col] = x[grow*DD + col] + acc[j][r] + bv;
        }
    }
}

// ---------------- launch ----------------
extern "C" void kernel_launch(void* const* d_in, const int* in_sizes, int n_in,
                              void* d_out, int out_size, void* d_ws, size_t ws_size,
                              hipStream_t stream)
{
    const float* x    = (const float*)d_in[0];
    const float* kW1  = (const float*)d_in[1];
    const float* kb1  = (const float*)d_in[2];
    const float* kW2  = (const float*)d_in[3];
    const float* kb2  = (const float*)d_in[4];
    const float* qW1  = (const float*)d_in[5];
    const float* qb1  = (const float*)d_in[6];
    const float* qW2  = (const float*)d_in[7];
    const float* qb2  = (const float*)d_in[8];
    const float* vW   = (const float*)d_in[9];
    const float* vb   = (const float*)d_in[10];
    const float* ln_g = (const float*)d_in[11];
    const float* ln_b = (const float*)d_in[12];
    const float* oW   = (const float*)d_in[13];
    const float* ob   = (const float*)d_in[14];
    const float* set_w= (const float*)d_in[15];
    const float* pf   = (const float*)d_in[16];
    const float* pw   = (const float*)d_in[17];
    const float* gW1  = (const float*)d_in[18];
    const float* gb1  = (const float*)d_in[19];
    const float* gW2  = (const float*)d_in[20];
    const float* gb2  = (const float*)d_in[21];
    const float* lW1  = (const float*)d_in[22];
    const float* lb1  = (const float*)d_in[23];
    const float* lW2  = (const float*)d_in[24];
    const float* lb2  = (const float*)d_in[25];
    const float* lvW  = (const float*)d_in[26];
    const float* lvb  = (const float*)d_in[27];
    const float* ss   = (const float*)d_in[28];
    const float* sb   = (const float*)d_in[29];
    const float* lw   = (const float*)d_in[30];
    float* out = (float*)d_out;

    float* ws    = (float*)d_ws;
    float* feat  = ws + FEAT_O;
    float* Vbuf  = ws + V_O;
    float* lval  = ws + LV_O;
    float* posph = ws + PPH_O;
    float* total = ws + TOT_O;
    float* cmem  = ws + CMEM_O;
    float* km    = ws + KM_O;
    float* wgbuf = ws + WGB_O;
    float* tot2  = ws + TOT2_O;
    unsigned short* xh   = (unsigned short*)(ws + XH_O);
    unsigned short* xl   = (unsigned short*)(ws + XL_O);
    unsigned short* wth  = (unsigned short*)(ws + WTH_O);
    unsigned short* wt2h = (unsigned short*)(ws + WT2H_O);
    unsigned short* owt  = (unsigned short*)(ws + OWT_O);

    (void)in_sizes; (void)n_in; (void)out_size; (void)ws_size;

    prep_all <<<512+192+48+8+32, 256, 0, stream>>>(x, kW1,qW1,lW1,vW,lvW,gW1, kW2,qW2,lW2,
                                                   oW, pf, xh, xl, wth, wt2h, owt, posph);
    mlp_fused<<<6*128, 256, 0, stream>>>(xh,xl,wth,wt2h,
                                         kb1,kb2, qb1,qb2, lb1,lb2,
                                         vb,lvb, gb1,gW2,gb2, feat, Vbuf, lval);
    g_prefix4<<<BB*10, 256, 0, stream>>>(feat, km);
    g_fam    <<<(BB*LL)/64, 64, 0, stream>>>(feat, km, ss, sb, wgbuf);
    m_chunksum_fam <<<BB*NC*2*3, 128, 0, stream>>>(feat, posph, wgbuf, Vbuf, lval, cmem);
    m_scan     <<<BB*NG*4*2, 256, 0, stream>>>(cmem);
    m_retrieve2 <<<BB*NC*2*2, 128, 0, stream>>>(feat, posph, wgbuf, Vbuf, lval, cmem,
                                                set_w, pw, lw, total, tot2);
    k4_mfma    <<<BB*LL/16, 256, 0, stream>>>(x, total, tot2, ln_g, ln_b, owt, ob, out);
}